// Round 15
// baseline (1179.898 us; speedup 1.0000x reference)
//
#include <hip/hip_runtime.h>
#include <hip/hip_bf16.h>
#include <stdint.h>

typedef short short8 __attribute__((ext_vector_type(8)));
typedef float floatx16 __attribute__((ext_vector_type(16)));

static constexpr int KTOT = 4096;
static constexpr int NTOT = 16384;
static constexpr int MTOT = 8192;

#define GLOAD_LDS16(g, l)                                              \
  __builtin_amdgcn_global_load_lds(                                    \
      (const __attribute__((address_space(1))) void*)(g),              \
      (__attribute__((address_space(3))) void*)(l), 16, 0, 0)

__device__ __forceinline__ uint32_t pack2_bf16_rne(float lo, float hi) {
  uint32_t a = __builtin_bit_cast(uint32_t, lo);
  uint32_t b = __builtin_bit_cast(uint32_t, hi);
  a += 0x7FFFu + ((a >> 16) & 1u);
  b += 0x7FFFu + ((b >> 16) & 1u);
  return __builtin_amdgcn_perm(b, a, 0x07060302u);  // hi16(b)<<16 | hi16(a)
}

// ---------------- converters ----------------

__global__ __launch_bounds__(256) void cvt_x_kernel(
    const float* __restrict__ X, ushort* __restrict__ Xb) {
  const size_t i = (size_t)blockIdx.x * 256 + threadIdx.x;  // 8 floats/thread
  const float4 a = *reinterpret_cast<const float4*>(X + i * 8);
  const float4 b = *reinterpret_cast<const float4*>(X + i * 8 + 4);
  uint4 o;
  o.x = pack2_bf16_rne(a.x, a.y);
  o.y = pack2_bf16_rne(a.z, a.w);
  o.z = pack2_bf16_rne(b.x, b.y);
  o.w = pack2_bf16_rne(b.z, b.w);
  *reinterpret_cast<uint4*>(Xb + i * 8) = o;
}

__global__ __launch_bounds__(256) void cvt_w_kernel(
    const uint32_t* __restrict__ Wp, ushort* __restrict__ Wb) {
  const size_t i = (size_t)blockIdx.x * 256 + threadIdx.x;  // 4 words -> 8 bf16
  const uint4 w = *reinterpret_cast<const uint4*>(Wp + i * 4);
  const uint32_t wd[4] = {w.x, w.y, w.z, w.w};
  uint4 o;
  uint32_t* op = reinterpret_cast<uint32_t*>(&o);
  #pragma unroll
  for (int p = 0; p < 4; ++p) {
    // each int32 word holds one packed byte: low nibble = value 2q, high = 2q+1
    int v0 = ((int)(wd[p] << 28)) >> 28;
    int v1 = ((int)(wd[p] << 24)) >> 28;
    uint32_t f0 = __builtin_bit_cast(uint32_t, (float)v0);  // exact in bf16
    uint32_t f1 = __builtin_bit_cast(uint32_t, (float)v1);
    op[p] = __builtin_amdgcn_perm(f1, f0, 0x07060302u);
  }
  *reinterpret_cast<uint4*>(Wb + i * 8) = o;
}

// ------- 256x256 bf16 GEMM: round-10 schedule (measured optimum) + 32x32x16 MFMA -------
// 512 threads = 8 waves (2 M x 4 N). Per-wave output 128x64 = 4x2 frags of 32x32,
// acc = floatx16[4][2] (128 regs, same as before).
// LDS: A ring 4 x 16KB + B ring 4 x 16KB = 128 KB; layout UNCHANGED (measured 0
// conflicts): ldsrow = m>>1, c_log = (m&1)<<2|kchunk, c_phys = c_log ^ (ldsrow&7).
// 32x32x16 operand mapping: A row = l&31, k = (l>>5)*8+j (extension of the
// HW-verified 16x16x32 pattern); per-frag read = 16B/lane at
// kchunk = (l>>5)+2*kh -> cph = ((l&1)<<2 | (l>>5)+2*kh) ^ (((l&31)>>1)&7);
// bank audit: each bank-quad hit exactly 8x per wave read = conflict-free floor.
// C/D (m74/m101-verified): col = lane&31, row = (reg&3)+8*(reg>>2)+4*(lane>>5).
// Why: 32x32 rate 2495 TF vs 16x16 2176 (µbench) and 16 vs 32 MFMA issue
// slots/tile -> MFMA pipe ~1183 -> ~1033 cyc/tile at identical LDS traffic.
// Schedule, staging, boundary, XCD map: r10 verbatim (all deviations measured worse).

static constexpr int BM = 256, BN = 256, BK = 32;
static constexpr int NT = KTOT / BK;  // 128 K-tiles

#define READ_FRAGS(AT, BT, buf)                                         \
  {                                                                     \
    const ushort* Ab_ = As + (buf) * 8192;                              \
    const ushort* Bb_ = Bs + (buf) * 8192;                              \
    _Pragma("unroll")                                                   \
    for (int fn = 0; fn < 2; ++fn) {                                    \
      BT[fn*2+0] = *reinterpret_cast<const short8*>(Bb_ + bbase2 + fn * 1024 + cA0); \
      BT[fn*2+1] = *reinterpret_cast<const short8*>(Bb_ + bbase2 + fn * 1024 + cA1); \
    }                                                                   \
    _Pragma("unroll")                                                   \
    for (int fm = 0; fm < 4; ++fm) {                                    \
      AT[fm*2+0] = *reinterpret_cast<const short8*>(Ab_ + abase2 + fm * 1024 + cA0); \
      AT[fm*2+1] = *reinterpret_cast<const short8*>(Ab_ + abase2 + fm * 1024 + cA1); \
    }                                                                   \
  }

#define STAGE(st_)                                                      \
  if ((st_) < NT) {                                                     \
    const int sb_ = (st_) & 3;                                          \
    const size_t kof_ = (size_t)(st_) * BK;                             \
    GLOAD_LDS16(agA + kof_,           aldsw + sb_ * 8192);              \
    GLOAD_LDS16(agA + kof_ + rowstep, aldsw + sb_ * 8192 + 4096);       \
    GLOAD_LDS16(agB + kof_,           bldsw + sb_ * 8192);              \
    GLOAD_LDS16(agB + kof_ + rowstep, bldsw + sb_ * 8192 + 4096);       \
  }

#define MFMA_CLUSTER(AT, BT)                                            \
  __builtin_amdgcn_s_setprio(1);                                        \
  _Pragma("unroll")                                                     \
  for (int kh = 0; kh < 2; ++kh)                                        \
    _Pragma("unroll")                                                   \
    for (int fm = 0; fm < 4; ++fm)                                      \
      _Pragma("unroll")                                                 \
      for (int fn = 0; fn < 2; ++fn)                                    \
        acc[fm][fn] = __builtin_amdgcn_mfma_f32_32x32x16_bf16(          \
            AT[fm*2+kh], BT[fn*2+kh], acc[fm][fn], 0, 0, 0);            \
  __builtin_amdgcn_s_setprio(0);

#define BOUNDARY(k_)                                                    \
  if ((k_) + 3 < NT) { asm volatile("s_waitcnt vmcnt(4)\ns_barrier" ::: "memory"); } \
  else               { asm volatile("s_waitcnt vmcnt(0)\ns_barrier" ::: "memory"); }

__global__ __launch_bounds__(512, 2) void gemm_bf16_256_kernel(
    const ushort* __restrict__ Xb,   // [MTOT][KTOT] bf16
    const ushort* __restrict__ Wb,   // [NTOT][KTOT] bf16 (B^T layout)
    const float* __restrict__ scale,
    const float* __restrict__ bias,
    float* __restrict__ Y)
{
  __shared__ ushort As[4 * 8192];   // buf*8192 + ldsrow*64 + c_phys*8
  __shared__ ushort Bs[4 * 8192];

  const int t    = threadIdx.x;
  const int lane = t & 63;
  const int wv   = t >> 6;       // 0..7
  const int wr   = wv >> 2;      // 0..1  (M half)
  const int wcn  = wv & 3;       // 0..3  (N quarter)

  // XCD mapping: xcd owns 4 M-tile rows; s>>2 sweeps N so all XCDs share W panels via L3
  const int wg  = blockIdx.x;          // 2048 blocks = 32 bm x 64 bn
  const int xcd = wg & 7;
  const int s   = wg >> 3;             // 0..255
  const int bm0 = (xcd * 4 + (s & 3)) * BM;
  const int bn0 = (s >> 2) * BN;

  // ---- staging addressing (pre-swizzled global source, linear LDS dest) — unchanged
  const int clg  = (t & 7) ^ ((t >> 3) & 7);
  const int srow = ((t >> 3) << 1) | (clg >> 2);
  const int scol = (clg & 3) * 8;
  const ushort* agA = Xb + (size_t)(bm0 + srow) * KTOT + scol;
  const ushort* agB = Wb + (size_t)(bn0 + srow) * KTOT + scol;
  const size_t rowstep = (size_t)128 * KTOT;   // second 64-ldsrow span (+128 M-rows)
  ushort* aldsw = As + wv * 512;               // wave-uniform base (+lane*16B by HW)
  ushort* bldsw = Bs + wv * 512;

  // ---- ds_read fragment addressing for 32x32x16 frags (conflict-free, audited)
  const int l31  = lane & 31;
  const int r7   = (l31 >> 1) & 7;
  const int cph0 = (((lane & 1) << 2) | (lane >> 5)) ^ r7;
  const int cA0  = cph0 * 8;            // kh=0 chunk byte-offset (in ushorts)
  const int cA1  = (cph0 ^ 2) * 8;      // kh=1 (kchunk +2 flips bit1)
  const int abase2 = (wr * 64 + (l31 >> 1)) * 64;   // + fm*1024
  const int bbase2 = (wcn * 32 + (l31 >> 1)) * 64;  // + fn*1024

  floatx16 acc[4][2];
  #pragma unroll
  for (int fm = 0; fm < 4; ++fm)
    #pragma unroll
    for (int fn = 0; fn < 2; ++fn)
      #pragma unroll
      for (int r = 0; r < 16; ++r)
        acc[fm][fn][r] = 0.f;

  // ---- prologue: stage tiles 0,1,2 (12 loads); publish tiles 0,1 (vmcnt(4))
  #pragma unroll
  for (int pt = 0; pt < 3; ++pt) {
    const size_t kof = (size_t)pt * BK;
    GLOAD_LDS16(agA + kof,           aldsw + pt * 8192);
    GLOAD_LDS16(agA + kof + rowstep, aldsw + pt * 8192 + 4096);
    GLOAD_LDS16(agB + kof,           bldsw + pt * 8192);
    GLOAD_LDS16(agB + kof + rowstep, bldsw + pt * 8192 + 4096);
  }
  asm volatile("s_waitcnt vmcnt(4)\ns_barrier" ::: "memory");

  // fragment sets (named; constant indices after unroll)
  short8 aTA[8], bTA[4];
  short8 aTB[8], bTB[4];
  READ_FRAGS(aTA, bTA, 0);   // tile 0 fragments

  for (int kt = 0; kt < NT; kt += 2) {
    // ---- even sub-iter: read tile kt+1 frags; stage kt+3; MFMA tile kt
    READ_FRAGS(aTB, bTB, (kt + 1) & 3);
    STAGE(kt + 3);
    MFMA_CLUSTER(aTA, bTA);
    BOUNDARY(kt);

    // ---- odd sub-iter: read tile kt+2 frags; stage kt+4; MFMA tile kt+1
    if (kt + 2 < NT) { READ_FRAGS(aTA, bTA, (kt + 2) & 3); }
    STAGE(kt + 4);
    MFMA_CLUSTER(aTB, bTB);
    if (kt + 2 < NT) { BOUNDARY(kt + 1); }
  }

  // ---- epilogue: y = acc * scale[col] + bias[col]
  // C/D 32x32: col = lane&31, row = (reg&3) + 8*(reg>>2) + 4*(lane>>5)  (m74/m101)
  const int rquad = (lane >> 5) * 4;
  #pragma unroll
  for (int fn = 0; fn < 2; ++fn) {
    const int col  = bn0 + wcn * 64 + fn * 32 + l31;
    const float sc = scale[col];
    const float bz = bias[col];
    #pragma unroll
    for (int fm = 0; fm < 4; ++fm) {
      const int rowb = bm0 + wr * 128 + fm * 32 + rquad;
      float* yp = Y + (size_t)rowb * NTOT + col;
      #pragma unroll
      for (int r = 0; r < 16; ++r)
        yp[(size_t)((r & 3) + 8 * (r >> 2)) * NTOT] = acc[fm][fn][r] * sc + bz;
    }
  }
}

// ---------------- fallback: fused kernel (round-2 passing version) ----------------

typedef float floatx4 __attribute__((ext_vector_type(4)));
static constexpr int FBM = 128, FBN = 128, FBK = 64;
static constexpr int LDSS = 72;
static constexpr int FNSTEP = KTOT / FBK;

__global__ __launch_bounds__(256) void int4_linear_fused_kernel(
    const float* __restrict__ X,
    const uint32_t* __restrict__ Wp,
    const float* __restrict__ scale,
    const float* __restrict__ bias,
    float* __restrict__ Y)
{
  __shared__ ushort As[FBM * LDSS];
  __shared__ ushort Bs[FBN * LDSS];

  const int t    = threadIdx.x;
  const int lane = t & 63;
  const int wv   = t >> 6;
  const int wr   = wv >> 1;
  const int wc   = wv & 1;
  const int bm0 = blockIdx.y * FBM;
  const int bn0 = blockIdx.x * FBN;
  const int srow = t >> 1;
  const int sh   = t & 1;

  const float*    ag = X  + (size_t)(bm0 + srow) * KTOT + sh * 32;
  const uint32_t* bg = Wp + (size_t)(bn0 + srow) * (KTOT / 2) + sh * 16;

  float4 areg[8];
  uint4  breg[4];
  #pragma unroll
  for (int j = 0; j < 8; ++j) areg[j] = *reinterpret_cast<const float4*>(ag + j * 4);
  #pragma unroll
  for (int j = 0; j < 4; ++j) breg[j] = *reinterpret_cast<const uint4*>(bg + j * 4);

  floatx4 acc[4][4];
  #pragma unroll
  for (int m = 0; m < 4; ++m)
    #pragma unroll
    for (int n = 0; n < 4; ++n)
      acc[m][n] = (floatx4){0.f, 0.f, 0.f, 0.f};

  ushort* adst = &As[srow * LDSS + sh * 32];
  ushort* bdst = &Bs[srow * LDSS + sh * 32];

  for (int ks = 0; ks < FNSTEP; ++ks) {
    {
      uint32_t ab[16];
      #pragma unroll
      for (int j = 0; j < 8; ++j) {
        uint32_t u0 = __builtin_bit_cast(uint32_t, areg[j].x) + 0x8000u;
        uint32_t u1 = __builtin_bit_cast(uint32_t, areg[j].y) + 0x8000u;
        uint32_t u2 = __builtin_bit_cast(uint32_t, areg[j].z) + 0x8000u;
        uint32_t u3 = __builtin_bit_cast(uint32_t, areg[j].w) + 0x8000u;
        ab[2*j]   = __builtin_amdgcn_perm(u1, u0, 0x07060302u);
        ab[2*j+1] = __builtin_amdgcn_perm(u3, u2, 0x07060302u);
      }
      uint32_t bb[16];
      #pragma unroll
      for (int j = 0; j < 4; ++j) {
        const uint32_t wq[4] = {breg[j].x, breg[j].y, breg[j].z, breg[j].w};
        #pragma unroll
        for (int p2 = 0; p2 < 4; ++p2) {
          const uint32_t w = wq[p2];
          int v0 = ((int)(w << 28)) >> 28;
          int v1 = ((int)(w << 24)) >> 28;
          uint32_t f0 = __builtin_bit_cast(uint32_t, (float)v0);
          uint32_t f1 = __builtin_bit_cast(uint32_t, (float)v1);
          bb[j*4 + p2] = __builtin_amdgcn_perm(f1, f0, 0x07060302u);
        }
      }
      #pragma unroll
      for (int j = 0; j < 4; ++j) {
        *reinterpret_cast<uint4*>(adst + j * 8) = *reinterpret_cast<const uint4*>(&ab[j*4]);
        *reinterpret_cast<uint4*>(bdst + j * 8) = *reinterpret_cast<const uint4*>(&bb[j*4]);
      }
    }
    __syncthreads();

    if (ks + 1 < FNSTEP) {
      const float*    ap = ag + (ks + 1) * FBK;
      const uint32_t* bp = bg + (ks + 1) * (FBK / 2);
      #pragma unroll
      for (int j = 0; j < 8; ++j) areg[j] = *reinterpret_cast<const float4*>(ap + j * 4);
      #pragma unroll
      for (int j = 0; j < 4; ++j) breg[j] = *reinterpret_cast<const uint4*>(bp + j * 4);
    }

    #pragma unroll
    for (int kk = 0; kk < 2; ++kk) {
      const int ko = kk * 32 + (lane >> 4) * 8;
      short8 af[4], bf[4];
      #pragma unroll
      for (int m = 0; m < 4; ++m)
        af[m] = *reinterpret_cast<const short8*>(&As[(wr*64 + m*16 + (lane & 15)) * LDSS + ko]);
      #pragma unroll
      for (int n = 0; n < 4; ++n)
        bf[n] = *reinterpret_cast<const short8*>(&Bs[(wc*64 + n*16 + (lane & 15)) * LDSS + ko]);
      #pragma unroll
      for (int m = 0; m < 4; ++m)
        #pragma unroll
        for (int n = 0; n < 4; ++n)
          acc[m][n] = __builtin_amdgcn_mfma_f32_16x16x32_bf16(af[m], bf[n], acc[m][n], 0, 0, 0);
    }
    __syncthreads();
  }

  const int crow = (lane >> 4) * 4;
  const int ccol = lane & 15;
  #pragma unroll
  for (int n = 0; n < 4; ++n) {
    const int col  = bn0 + wc * 64 + n * 16 + ccol;
    const float sv = scale[col];
    const float bz = bias[col];
    #pragma unroll
    for (int m = 0; m < 4; ++m) {
      const int row0 = bm0 + wr * 64 + m * 16 + crow;
      float* yp = Y + (size_t)row0 * NTOT + col;
      #pragma unroll
      for (int r = 0; r < 4; ++r)
        yp[(size_t)r * NTOT] = acc[m][n][r] * sv + bz;
    }
  }
}

// ---------------- launch ----------------

extern "C" void kernel_launch(void* const* d_in, const int* in_sizes, int n_in,
                              void* d_out, int out_size, void* d_ws, size_t ws_size,
                              hipStream_t stream) {
  (void)in_sizes; (void)n_in; (void)out_size;
  const float*    X     = (const float*)d_in[0];
  const uint32_t* Wp    = (const uint32_t*)d_in[1];
  const float*    scale = (const float*)d_in[2];
  const float*    bias  = (const float*)d_in[3];
  float*          Y     = (float*)d_out;

  const size_t xb_bytes = (size_t)MTOT * KTOT * 2;          // 67 MB
  const size_t wb_bytes = (size_t)NTOT * KTOT * 2;          // 134 MB
  if (ws_size >= xb_bytes + wb_bytes) {
    ushort* Xb = (ushort*)d_ws;
    ushort* Wb = (ushort*)((char*)d_ws + xb_bytes);
    cvt_x_kernel<<<(MTOT * KTOT) / (8 * 256), 256, 0, stream>>>(X, Xb);
    cvt_w_kernel<<<(NTOT * KTOT / 2) / (4 * 256), 256, 0, stream>>>(Wp, Wb);
    gemm_bf16_256_kernel<<<(MTOT / BM) * (NTOT / BN), 512, 0, stream>>>(Xb, Wb, scale, bias, Y);
  } else {
    dim3 grid(NTOT / FBN, MTOT / FBM);
    int4_linear_fused_kernel<<<grid, 256, 0, stream>>>(X, Wp, scale, bias, Y);
  }
}

// Round 16
// 1081.052 us; speedup vs baseline: 1.0914x; 1.0914x over previous
//
#include <hip/hip_runtime.h>
#include <hip/hip_bf16.h>
#include <stdint.h>

typedef short short8 __attribute__((ext_vector_type(8)));
typedef float floatx4 __attribute__((ext_vector_type(4)));

static constexpr int KTOT = 4096;
static constexpr int NTOT = 16384;
static constexpr int MTOT = 8192;

#define GLOAD_LDS16(g, l)                                              \
  __builtin_amdgcn_global_load_lds(                                    \
      (const __attribute__((address_space(1))) void*)(g),              \
      (__attribute__((address_space(3))) void*)(l), 16, 0, 0)

__device__ __forceinline__ uint32_t pack2_bf16_rne(float lo, float hi) {
  uint32_t a = __builtin_bit_cast(uint32_t, lo);
  uint32_t b = __builtin_bit_cast(uint32_t, hi);
  a += 0x7FFFu + ((a >> 16) & 1u);
  b += 0x7FFFu + ((b >> 16) & 1u);
  return __builtin_amdgcn_perm(b, a, 0x07060302u);  // hi16(b)<<16 | hi16(a)
}

// ---------------- converters ----------------

__global__ __launch_bounds__(256) void cvt_x_kernel(
    const float* __restrict__ X, ushort* __restrict__ Xb) {
  const size_t i = (size_t)blockIdx.x * 256 + threadIdx.x;  // 8 floats/thread
  const float4 a = *reinterpret_cast<const float4*>(X + i * 8);
  const float4 b = *reinterpret_cast<const float4*>(X + i * 8 + 4);
  uint4 o;
  o.x = pack2_bf16_rne(a.x, a.y);
  o.y = pack2_bf16_rne(a.z, a.w);
  o.z = pack2_bf16_rne(b.x, b.y);
  o.w = pack2_bf16_rne(b.z, b.w);
  *reinterpret_cast<uint4*>(Xb + i * 8) = o;
}

__global__ __launch_bounds__(256) void cvt_w_kernel(
    const uint32_t* __restrict__ Wp, ushort* __restrict__ Wb) {
  const size_t i = (size_t)blockIdx.x * 256 + threadIdx.x;  // 4 words -> 8 bf16
  const uint4 w = *reinterpret_cast<const uint4*>(Wp + i * 4);
  const uint32_t wd[4] = {w.x, w.y, w.z, w.w};
  uint4 o;
  uint32_t* op = reinterpret_cast<uint32_t*>(&o);
  #pragma unroll
  for (int p = 0; p < 4; ++p) {
    // each int32 word holds one packed byte: low nibble = value 2q, high = 2q+1
    int v0 = ((int)(wd[p] << 28)) >> 28;
    int v1 = ((int)(wd[p] << 24)) >> 28;
    uint32_t f0 = __builtin_bit_cast(uint32_t, (float)v0);  // exact in bf16
    uint32_t f1 = __builtin_bit_cast(uint32_t, (float)v1);
    op[p] = __builtin_amdgcn_perm(f1, f0, 0x07060302u);
  }
  *reinterpret_cast<uint4*>(Wb + i * 8) = o;
}

// ------- 256x256 bf16 GEMM: round-10 structure (measured optimum) — FINAL -------
// 512 threads = 8 waves (2 M x 4 N). Per-wave output 128x64 -> acc[8][4].
// LDS: A ring 4 x 16KB + B ring 4 x 16KB = 128 KB (1 block/CU).
// Layout (measured 0 bank conflicts WITH the 16x16 read geometry): BK=32 tile as
// 128-B LDS rows, two M-rows per LDS row: ldsrow = m>>1, c_log = (m&1)<<2|kchunk,
// c_phys = c_log ^ (ldsrow&7).
// Schedule (best of r7..r15 ladder, MfmaUtil ~52%): iter kt reads tile kt+1's 12
// fragments FIRST, then stages tile kt+3, then MFMAs tile kt from last iter's
// regs; single boundary asm{vmcnt(4); s_barrier} per tile publishes kt+2.
// MEASURED DEAD ENDS (do not revisit): 4-phase drain0 (38%), 2-phase counted
// (41%), stage-first + split-read order (34%), B via L2 gather (28%),
// 32x32x16 MFMA on this layout (43%, conflicts return — layout is geometry-
// specific). Layout+schedule are co-designed; change neither in isolation.

static constexpr int BM = 256, BN = 256, BK = 32;
static constexpr int NT = KTOT / BK;  // 128 K-tiles

#define READ_FRAGS(AF0, AF1, BF, buf)                                   \
  {                                                                     \
    const ushort* Ab_ = As + (buf) * 8192 + abase + laneoff;            \
    const ushort* Bb_ = Bs + (buf) * 8192 + bbase + laneoff;            \
    _Pragma("unroll")                                                   \
    for (int n = 0; n < 4; ++n)                                         \
      BF[n] = *reinterpret_cast<const short8*>(Bb_ + n * 512);          \
    _Pragma("unroll")                                                   \
    for (int m = 0; m < 4; ++m)                                         \
      AF0[m] = *reinterpret_cast<const short8*>(Ab_ + m * 512);         \
    _Pragma("unroll")                                                   \
    for (int m = 0; m < 4; ++m)                                         \
      AF1[m] = *reinterpret_cast<const short8*>(Ab_ + (m + 4) * 512);   \
  }

#define STAGE(st_)                                                      \
  if ((st_) < NT) {                                                     \
    const int sb_ = (st_) & 3;                                          \
    const size_t kof_ = (size_t)(st_) * BK;                             \
    GLOAD_LDS16(agA + kof_,           aldsw + sb_ * 8192);              \
    GLOAD_LDS16(agA + kof_ + rowstep, aldsw + sb_ * 8192 + 4096);       \
    GLOAD_LDS16(agB + kof_,           bldsw + sb_ * 8192);              \
    GLOAD_LDS16(agB + kof_ + rowstep, bldsw + sb_ * 8192 + 4096);       \
  }

#define MFMA_CLUSTER(AF0, AF1, BF)                                      \
  __builtin_amdgcn_s_setprio(1);                                        \
  _Pragma("unroll")                                                     \
  for (int m = 0; m < 4; ++m)                                           \
    _Pragma("unroll")                                                   \
    for (int n = 0; n < 4; ++n)                                         \
      acc[m][n] = __builtin_amdgcn_mfma_f32_16x16x32_bf16(AF0[m], BF[n], acc[m][n], 0, 0, 0); \
  _Pragma("unroll")                                                     \
  for (int m = 0; m < 4; ++m)                                           \
    _Pragma("unroll")                                                   \
    for (int n = 0; n < 4; ++n)                                         \
      acc[m + 4][n] = __builtin_amdgcn_mfma_f32_16x16x32_bf16(AF1[m], BF[n], acc[m + 4][n], 0, 0, 0); \
  __builtin_amdgcn_s_setprio(0);

#define BOUNDARY(k_)                                                    \
  if ((k_) + 3 < NT) { asm volatile("s_waitcnt vmcnt(4)\ns_barrier" ::: "memory"); } \
  else               { asm volatile("s_waitcnt vmcnt(0)\ns_barrier" ::: "memory"); }

__global__ __launch_bounds__(512, 2) void gemm_bf16_256_kernel(
    const ushort* __restrict__ Xb,   // [MTOT][KTOT] bf16
    const ushort* __restrict__ Wb,   // [NTOT][KTOT] bf16 (B^T layout)
    const float* __restrict__ scale,
    const float* __restrict__ bias,
    float* __restrict__ Y)
{
  __shared__ ushort As[4 * 8192];   // buf*8192 + ldsrow*64 + c_phys*8
  __shared__ ushort Bs[4 * 8192];

  const int t    = threadIdx.x;
  const int lane = t & 63;
  const int wv   = t >> 6;       // 0..7
  const int wr   = wv >> 2;      // 0..1  (M half)
  const int wcn  = wv & 3;       // 0..3  (N quarter)

  // XCD mapping: xcd owns 4 M-tile rows; s>>2 sweeps N so all XCDs share W panels via L3
  const int wg  = blockIdx.x;          // 2048 blocks = 32 bm x 64 bn
  const int xcd = wg & 7;
  const int s   = wg >> 3;             // 0..255
  const int bm0 = (xcd * 4 + (s & 3)) * BM;
  const int bn0 = (s >> 2) * BN;

  // ---- staging addressing (pre-swizzled global source, linear LDS dest)
  const int clg  = (t & 7) ^ ((t >> 3) & 7);
  const int srow = ((t >> 3) << 1) | (clg >> 2);
  const int scol = (clg & 3) * 8;
  const ushort* agA = Xb + (size_t)(bm0 + srow) * KTOT + scol;
  const ushort* agB = Wb + (size_t)(bn0 + srow) * KTOT + scol;
  const size_t rowstep = (size_t)128 * KTOT;   // second 64-ldsrow span (+128 M-rows)
  ushort* aldsw = As + wv * 512;               // wave-uniform base (+lane*16B by HW)
  ushort* bldsw = Bs + wv * 512;

  // ---- ds_read fragment addressing (conflict-free XOR layout)
  const int p    = lane >> 4;
  const int l15  = lane & 15;
  const int cph  = (((l15 & 1) << 2) | p) ^ ((l15 >> 1) & 7);
  const int laneoff = (l15 >> 1) * 64 + cph * 8;
  const int abase = wr * 4096;    // wr*64 ldsrows * 64 ushorts
  const int bbase = wcn * 2048;   // wcn*32 ldsrows

  floatx4 acc[8][4];
  #pragma unroll
  for (int m = 0; m < 8; ++m)
    #pragma unroll
    for (int n = 0; n < 4; ++n)
      acc[m][n] = (floatx4){0.f, 0.f, 0.f, 0.f};

  // ---- prologue: stage tiles 0,1,2 (12 loads); publish tiles 0,1 (vmcnt(4))
  #pragma unroll
  for (int pt = 0; pt < 3; ++pt) {
    const size_t kof = (size_t)pt * BK;
    GLOAD_LDS16(agA + kof,           aldsw + pt * 8192);
    GLOAD_LDS16(agA + kof + rowstep, aldsw + pt * 8192 + 4096);
    GLOAD_LDS16(agB + kof,           bldsw + pt * 8192);
    GLOAD_LDS16(agB + kof + rowstep, bldsw + pt * 8192 + 4096);
  }
  asm volatile("s_waitcnt vmcnt(4)\ns_barrier" ::: "memory");

  // fragment sets (named; no runtime-indexed reg arrays)
  short8 a0A[4], a1A[4], bA[4];
  short8 a0B[4], a1B[4], bB[4];
  READ_FRAGS(a0A, a1A, bA, 0);   // tile 0 fragments

  for (int kt = 0; kt < NT; kt += 2) {
    // ---- even sub-iter: read tile kt+1 frags; stage kt+3; MFMA tile kt
    READ_FRAGS(a0B, a1B, bB, (kt + 1) & 3);
    STAGE(kt + 3);
    MFMA_CLUSTER(a0A, a1A, bA);
    BOUNDARY(kt);

    // ---- odd sub-iter: read tile kt+2 frags; stage kt+4; MFMA tile kt+1
    if (kt + 2 < NT) { READ_FRAGS(a0A, a1A, bA, (kt + 2) & 3); }
    STAGE(kt + 4);
    MFMA_CLUSTER(a0B, a1B, bB);
    if (kt + 2 < NT) { BOUNDARY(kt + 1); }
  }

  // ---- epilogue: y = acc * scale[col] + bias[col]
  const int crow = (lane >> 4) * 4;  // C/D: row=(lane>>4)*4+reg, col=lane&15 (m89)
  const int ccol = lane & 15;
  #pragma unroll
  for (int n = 0; n < 4; ++n) {
    const int col  = bn0 + wcn * 64 + n * 16 + ccol;
    const float sc = scale[col];
    const float bz = bias[col];
    #pragma unroll
    for (int m = 0; m < 8; ++m) {
      const int row0 = bm0 + wr * 128 + m * 16 + crow;
      float* yp = Y + (size_t)row0 * NTOT + col;
      #pragma unroll
      for (int r = 0; r < 4; ++r)
        yp[(size_t)r * NTOT] = acc[m][n][r] * sc + bz;
    }
  }
}

// ---------------- fallback: fused kernel (round-2 passing version) ----------------

static constexpr int FBM = 128, FBN = 128, FBK = 64;
static constexpr int LDSS = 72;
static constexpr int FNSTEP = KTOT / FBK;

__global__ __launch_bounds__(256) void int4_linear_fused_kernel(
    const float* __restrict__ X,
    const uint32_t* __restrict__ Wp,
    const float* __restrict__ scale,
    const float* __restrict__ bias,
    float* __restrict__ Y)
{
  __shared__ ushort As[FBM * LDSS];
  __shared__ ushort Bs[FBN * LDSS];

  const int t    = threadIdx.x;
  const int lane = t & 63;
  const int wv   = t >> 6;
  const int wr   = wv >> 1;
  const int wc   = wv & 1;
  const int bm0 = blockIdx.y * FBM;
  const int bn0 = blockIdx.x * FBN;
  const int srow = t >> 1;
  const int sh   = t & 1;

  const float*    ag = X  + (size_t)(bm0 + srow) * KTOT + sh * 32;
  const uint32_t* bg = Wp + (size_t)(bn0 + srow) * (KTOT / 2) + sh * 16;

  float4 areg[8];
  uint4  breg[4];
  #pragma unroll
  for (int j = 0; j < 8; ++j) areg[j] = *reinterpret_cast<const float4*>(ag + j * 4);
  #pragma unroll
  for (int j = 0; j < 4; ++j) breg[j] = *reinterpret_cast<const uint4*>(bg + j * 4);

  floatx4 acc[4][4];
  #pragma unroll
  for (int m = 0; m < 4; ++m)
    #pragma unroll
    for (int n = 0; n < 4; ++n)
      acc[m][n] = (floatx4){0.f, 0.f, 0.f, 0.f};

  ushort* adst = &As[srow * LDSS + sh * 32];
  ushort* bdst = &Bs[srow * LDSS + sh * 32];

  for (int ks = 0; ks < FNSTEP; ++ks) {
    {
      uint32_t ab[16];
      #pragma unroll
      for (int j = 0; j < 8; ++j) {
        uint32_t u0 = __builtin_bit_cast(uint32_t, areg[j].x) + 0x8000u;
        uint32_t u1 = __builtin_bit_cast(uint32_t, areg[j].y) + 0x8000u;
        uint32_t u2 = __builtin_bit_cast(uint32_t, areg[j].z) + 0x8000u;
        uint32_t u3 = __builtin_bit_cast(uint32_t, areg[j].w) + 0x8000u;
        ab[2*j]   = __builtin_amdgcn_perm(u1, u0, 0x07060302u);
        ab[2*j+1] = __builtin_amdgcn_perm(u3, u2, 0x07060302u);
      }
      uint32_t bb[16];
      #pragma unroll
      for (int j = 0; j < 4; ++j) {
        const uint32_t wq[4] = {breg[j].x, breg[j].y, breg[j].z, breg[j].w};
        #pragma unroll
        for (int p2 = 0; p2 < 4; ++p2) {
          const uint32_t w = wq[p2];
          int v0 = ((int)(w << 28)) >> 28;
          int v1 = ((int)(w << 24)) >> 28;
          uint32_t f0 = __builtin_bit_cast(uint32_t, (float)v0);
          uint32_t f1 = __builtin_bit_cast(uint32_t, (float)v1);
          bb[j*4 + p2] = __builtin_amdgcn_perm(f1, f0, 0x07060302u);
        }
      }
      #pragma unroll
      for (int j = 0; j < 4; ++j) {
        *reinterpret_cast<uint4*>(adst + j * 8) = *reinterpret_cast<const uint4*>(&ab[j*4]);
        *reinterpret_cast<uint4*>(bdst + j * 8) = *reinterpret_cast<const uint4*>(&bb[j*4]);
      }
    }
    __syncthreads();

    if (ks + 1 < FNSTEP) {
      const float*    ap = ag + (ks + 1) * FBK;
      const uint32_t* bp = bg + (ks + 1) * (FBK / 2);
      #pragma unroll
      for (int j = 0; j < 8; ++j) areg[j] = *reinterpret_cast<const float4*>(ap + j * 4);
      #pragma unroll
      for (int j = 0; j < 4; ++j) breg[j] = *reinterpret_cast<const uint4*>(bp + j * 4);
    }

    #pragma unroll
    for (int kk = 0; kk < 2; ++kk) {
      const int ko = kk * 32 + (lane >> 4) * 8;
      short8 af[4], bf[4];
      #pragma unroll
      for (int m = 0; m < 4; ++m)
        af[m] = *reinterpret_cast<const short8*>(&As[(wr*64 + m*16 + (lane & 15)) * LDSS + ko]);
      #pragma unroll
      for (int n = 0; n < 4; ++n)
        bf[n] = *reinterpret_cast<const short8*>(&Bs[(wc*64 + n*16 + (lane & 15)) * LDSS + ko]);
      #pragma unroll
      for (int m = 0; m < 4; ++m)
        #pragma unroll
        for (int n = 0; n < 4; ++n)
          acc[m][n] = __builtin_amdgcn_mfma_f32_16x16x32_bf16(af[m], bf[n], acc[m][n], 0, 0, 0);
    }
    __syncthreads();
  }

  const int crow = (lane >> 4) * 4;
  const int ccol = lane & 15;
  #pragma unroll
  for (int n = 0; n < 4; ++n) {
    const int col  = bn0 + wc * 64 + n * 16 + ccol;
    const float sv = scale[col];
    const float bz = bias[col];
    #pragma unroll
    for (int m = 0; m < 4; ++m) {
      const int row0 = bm0 + wr * 64 + m * 16 + crow;
      float* yp = Y + (size_t)row0 * NTOT + col;
      #pragma unroll
      for (int r = 0; r < 4; ++r)
        yp[(size_t)r * NTOT] = acc[m][n][r] * sv + bz;
    }
  }
}

// ---------------- launch ----------------

extern "C" void kernel_launch(void* const* d_in, const int* in_sizes, int n_in,
                              void* d_out, int out_size, void* d_ws, size_t ws_size,
                              hipStream_t stream) {
  (void)in_sizes; (void)n_in; (void)out_size;
  const float*    X     = (const float*)d_in[0];
  const uint32_t* Wp    = (const uint32_t*)d_in[1];
  const float*    scale = (const float*)d_in[2];
  const float*    bias  = (const float*)d_in[3];
  float*          Y     = (float*)d_out;

  const size_t xb_bytes = (size_t)MTOT * KTOT * 2;          // 67 MB
  const size_t wb_bytes = (size_t)NTOT * KTOT * 2;          // 134 MB
  if (ws_size >= xb_bytes + wb_bytes) {
    ushort* Xb = (ushort*)d_ws;
    ushort* Wb = (ushort*)((char*)d_ws + xb_bytes);
    cvt_x_kernel<<<(MTOT * KTOT) / (8 * 256), 256, 0, stream>>>(X, Xb);
    cvt_w_kernel<<<(NTOT * KTOT / 2) / (4 * 256), 256, 0, stream>>>(Wp, Wb);
    gemm_bf16_256_kernel<<<(MTOT / BM) * (NTOT / BN), 512, 0, stream>>>(Xb, Wb, scale, bias, Y);
  } else {
    dim3 grid(NTOT / FBN, MTOT / FBM);
    int4_linear_fused_kernel<<<grid, 256, 0, stream>>>(X, Wp, scale, bias, Y);
  }
}